// Round 3
// baseline (268.627 us; speedup 1.0000x reference)
//
#include <hip/hip_runtime.h>

#define BATCH 2
#define CDIM 256
#define NPIX 2304      // 48*48
#define NHEAD 8
#define DH 64
#define HID 512
#define NMEM 4
#define NKV 2308       // NMEM + NPIX
#define NKVP 2368      // NKV padded to multiple of 64 (zeroed pad)
#define QSCALE 0.125f  // 64^-0.5
#define LOG2E 1.4426950408889634f
#define WQKV_E 393216  // 1536*256
#define WOUT_E 131072  // 256*512

typedef float f32x4 __attribute__((ext_vector_type(4)));
typedef __bf16 bf16x8 __attribute__((ext_vector_type(8)));
typedef unsigned short u16;
typedef u16 u16x4 __attribute__((ext_vector_type(4)));
typedef u16 u16x8 __attribute__((ext_vector_type(8)));
typedef unsigned u32x2 __attribute__((ext_vector_type(2)));

#if __has_builtin(__builtin_amdgcn_exp2f)
#define EXP2(x) __builtin_amdgcn_exp2f(x)
#else
#define EXP2(x) exp2f(x)
#endif

static __device__ __forceinline__ u16 f2b(float f) {
  union { float f; unsigned u; } a; a.f = f;
  unsigned u = a.u;
  u += 0x7fffu + ((u >> 16) & 1u);   // RNE
  return (u16)(u >> 16);
}

// ---------------- Kernel 1: RMSNorm -> xn^T bf16 [b*p][c] -----------------------
// grid 72 (64 pixels/block), block 256
__global__ __launch_bounds__(256) void k_norm(
    const float* __restrict__ x, const float* __restrict__ gamma, u16* __restrict__ xnT)
{
  __shared__ float xs[64][257];
  __shared__ float red[4][64];
  __shared__ float rsh[64];
  __shared__ float g1[CDIM];
  const int t = threadIdx.x;
  const int bp0 = blockIdx.x * 64;
  const int bb = bp0 >= NPIX;
  const int p0 = bp0 - bb * NPIX;
  g1[t] = 1.0f + gamma[t];
  const float* xb = x + (size_t)bb * CDIM * NPIX;
  const int pq = (t & 15) * 4;
  const int cq0 = t >> 4;
#pragma unroll
  for (int it = 0; it < 16; ++it) {
    const int c = it * 16 + cq0;
    const f32x4 v = *(const f32x4*)&xb[(size_t)c * NPIX + p0 + pq];
    xs[pq + 0][c] = v[0]; xs[pq + 1][c] = v[1];
    xs[pq + 2][c] = v[2]; xs[pq + 3][c] = v[3];
  }
  __syncthreads();
  {
    const int p = t & 63, cg = t >> 6;
    float ssq = 0.f;
#pragma unroll
    for (int i = 0; i < 64; ++i) { const float v = xs[p][cg * 64 + i]; ssq += v * v; }
    red[cg][p] = ssq;
  }
  __syncthreads();
  if (t < 64) {
    const float s = red[0][t] + red[1][t] + red[2][t] + red[3][t];
    rsh[t] = 16.0f / fmaxf(sqrtf(s), 1e-12f);   // sqrt(CDIM)=16
  }
  __syncthreads();
#pragma unroll
  for (int it = 0; it < 8; ++it) {
    const int idx = it * 256 + t;
    const int pp = idx >> 5, c0 = (idx & 31) * 8;
    const float rs = rsh[pp];
    u16x8 o;
#pragma unroll
    for (int e = 0; e < 8; ++e) o[e] = f2b(xs[pp][c0 + e] * rs * g1[c0 + e]);
    *(u16x8*)&xnT[(size_t)(bp0 + pp) * CDIM + c0] = o;
  }
}

// ---------------- Kernel 2: cast weights to bf16 (QSCALE*log2e into q rows) -----
// grid 256, block 256; wb = [wqkv bf16 (1536x256) | wout bf16 (256x512)]
__global__ __launch_bounds__(256) void k_prep_w(
    const float* __restrict__ wqkv, const float* __restrict__ wout, u16* __restrict__ wb)
{
  const int i0 = (blockIdx.x * 256 + threadIdx.x) * 8;
  const float* src;
  float sc = 1.0f;
  if (i0 < WQKV_E) { src = wqkv + i0; if ((i0 >> 8) < 512) sc = QSCALE * LOG2E; }
  else             { src = wout + (i0 - WQKV_E); }
  const f32x4 a = *(const f32x4*)src;
  const f32x4 b = *(const f32x4*)(src + 4);
  u16x8 o;
#pragma unroll
  for (int e = 0; e < 4; ++e) { o[e] = f2b(a[e] * sc); o[e + 4] = f2b(b[e] * sc); }
  *(u16x8*)&wb[i0] = o;
}

// ---------------- Kernel 3a: zero vT tail (kv 2304..2367) -----------------------
// grid 64, block 256: 1024 (bh,d) rows x 16 threads x u16x4
__global__ __launch_bounds__(256) void k_zeropad(u16* __restrict__ vT)
{
  const int gid = blockIdx.x * 256 + threadIdx.x;     // 0..16383
  const int row = gid >> 4;                            // bh*64+d
  const int c0 = (gid & 15) * 4 + 2304;
  u16x4 z = {0, 0, 0, 0};
  *(u16x4*)&vT[(size_t)row * NKVP + c0] = z;
}

// ---------------- Kernel 3b: fill memory kv tokens (kv rows 0..3) ---------------
__global__ __launch_bounds__(256) void k_fillmem(const float* __restrict__ mem_kv,
                                                 u16* __restrict__ kk, u16* __restrict__ vT)
{
  const int idx = blockIdx.x * 256 + threadIdx.x;  // 0..4095 = b,h,m,d
  const int d = idx & 63;
  const int m = (idx >> 6) & 3;
  const int h = (idx >> 8) & 7;
  const int b = idx >> 11;
  const float mk = mem_kv[((size_t)h * NMEM + m) * DH + d];
  const float mv = mem_kv[(((size_t)NHEAD + h) * NMEM + m) * DH + d];
  kk[(((size_t)(b * NHEAD + h)) * NKV + m) * DH + d] = f2b(mk);
  vT[(((size_t)(b * NHEAD + h)) * DH + d) * NKVP + m] = f2b(mv);
}

// ---------------- Kernel 4: QKV projection GEMM (bf16 MFMA) ---------------------
// C[p][o] = sum_c xnT[p][c] * wb[o][c];  grid (72, 24), block 256 (4 waves x 16 rows)
__global__ __launch_bounds__(256) void k_qkv(
    const u16* __restrict__ xnT, const u16* __restrict__ wb,
    u16* __restrict__ q, u16* __restrict__ kk, u16* __restrict__ vT)
{
  const int t = threadIdx.x, w = t >> 6, l = t & 63, li = l & 15, kg = l >> 4;
  const int m0 = blockIdx.x * 64 + w * 16;
  const int n0 = blockIdx.y * 64;
  const u16* ap = xnT + (size_t)(m0 + li) * CDIM + kg * 8;
  f32x4 acc[4];
#pragma unroll
  for (int cf = 0; cf < 4; ++cf) { f32x4 z = {0.f,0.f,0.f,0.f}; acc[cf] = z; }
#pragma unroll
  for (int ks = 0; ks < 8; ++ks) {
    const bf16x8 af = *(const bf16x8*)(ap + ks * 32);
#pragma unroll
    for (int cf = 0; cf < 4; ++cf) {
      const int o = n0 + cf * 16 + li;
      const bf16x8 bfr = *(const bf16x8*)(wb + (size_t)o * CDIM + ks * 32 + kg * 8);
      acc[cf] = __builtin_amdgcn_mfma_f32_16x16x32_bf16(af, bfr, acc[cf], 0, 0, 0);
    }
  }
  const int bb = (m0 >= NPIX) ? 1 : 0;
  const int plbase = m0 - bb * NPIX + kg * 4;
#pragma unroll
  for (int cf = 0; cf < 4; ++cf) {
    const int o0f = n0 + cf * 16;          // uniform over lanes
    const int r = o0f >> 9, oo = o0f & 511, h = oo >> 6, d = (oo & 63) + li;
    if (r == 0) {
      u16* base = q + ((size_t)(bb * NHEAD + h) * NPIX + plbase) * DH + d;
#pragma unroll
      for (int rr = 0; rr < 4; ++rr) base[(size_t)rr * DH] = f2b(acc[cf][rr]);
    } else if (r == 1) {
      u16* base = kk + ((size_t)(bb * NHEAD + h) * NKV + NMEM + plbase) * DH + d;
#pragma unroll
      for (int rr = 0; rr < 4; ++rr) base[(size_t)rr * DH] = f2b(acc[cf][rr]);
    } else {
      // transposed V: vT[bh][d][kv], 4 consecutive kv per lane -> one 8B store
      u16x4 pk;
#pragma unroll
      for (int rr = 0; rr < 4; ++rr) pk[rr] = f2b(acc[cf][rr]);
      *(u16x4*)&vT[(((size_t)(bb * NHEAD + h)) * DH + d) * NKVP + NMEM + plbase] = pk;
    }
  }
}

// ---------------- Kernel 5: flash attention, swapped-QK^T, no barriers in loop --
// grid (36, 16); block 512 = 8 waves: (qsub 0..3) x (half 0..1); 16 q-rows/wave
__global__ __launch_bounds__(512) void k_attn(
    const u16* __restrict__ q, const u16* __restrict__ kk, const u16* __restrict__ vT,
    u16* __restrict__ aoB)
{
  __shared__ __align__(16) u16 ps[8][16 * 72];   // per-wave P (bf16), q-major rows
  __shared__ float accbuf[4][16][67];            // h=1 partial acc [qsub][q][d]
  __shared__ float mlbuf[4][16][2];              // h=1 partial m,l  [qsub][q]
  const int t = threadIdx.x;
  const int w = t >> 6, l = t & 63;
  const int qsub = w & 3, hf = w >> 2;
  const int li = l & 15, kg = l >> 4;
  const int bh = blockIdx.y;
  const int b = bh >> 3, hh = bh & 7;
  const int qrow0 = blockIdx.x * 64 + qsub * 16;
  const u16* qp = q + ((size_t)bh * NPIX + qrow0) * DH;
  const u16* kp = kk + (size_t)bh * NKV * DH;
  const u16* vp = vT + (size_t)bh * DH * NKVP;

  // Q B-fragment (persistent): lane (li,kg) holds Q[q=li][d=kg*8+e]
  const bf16x8 bq0 = *(const bf16x8*)&qp[li * DH + kg * 8];
  const bf16x8 bq1 = *(const bf16x8*)&qp[li * DH + 32 + kg * 8];

  f32x4 acc[4];
#pragma unroll
  for (int df = 0; df < 4; ++df) { f32x4 z = {0.f,0.f,0.f,0.f}; acc[df] = z; }
  float m = -1e30f, lsum = 0.f;   // for q = li (uniform across kg)

  const int t0 = hf ? 19 : 0, t1 = hf ? 37 : 19;
  for (int tile = t0; tile < t1; ++tile) {
    const int kbase = tile * 64;
    const bool lastt = (kbase + 64 > NKV);   // wave-uniform
    // S^T = K . Q^T : A = K rows (kv), B = Q. C: lane holds kv=kg*4+r, q=li.
    f32x4 s[4];
#pragma unroll
    for (int jf = 0; jf < 4; ++jf) {
      int kvr = kbase + jf * 16 + li;
      if (lastt) kvr = (kvr < NKV) ? kvr : (NKV - 1);
      const bf16x8 ak0 = *(const bf16x8*)&kp[(size_t)kvr * DH + kg * 8];
      const bf16x8 ak1 = *(const bf16x8*)&kp[(size_t)kvr * DH + 32 + kg * 8];
      f32x4 sf = {0.f, 0.f, 0.f, 0.f};
      sf = __builtin_amdgcn_mfma_f32_16x16x32_bf16(ak0, bq0, sf, 0, 0, 0);
      sf = __builtin_amdgcn_mfma_f32_16x16x32_bf16(ak1, bq1, sf, 0, 0, 0);
      s[jf] = sf;
    }
    if (lastt) {
#pragma unroll
      for (int jf = 0; jf < 4; ++jf)
#pragma unroll
        for (int r = 0; r < 4; ++r)
          if (kbase + jf * 16 + kg * 4 + r >= NKV) s[jf][r] = -1e30f;
    }
    // row max (row = q = li): local 16-value tree + 2 shfls
    float pmax = fmaxf(fmaxf(fmaxf(s[0][0], s[0][1]), fmaxf(s[0][2], s[0][3])),
                       fmaxf(fmaxf(s[1][0], s[1][1]), fmaxf(s[1][2], s[1][3])));
    pmax = fmaxf(pmax, fmaxf(fmaxf(fmaxf(s[2][0], s[2][1]), fmaxf(s[2][2], s[2][3])),
                             fmaxf(fmaxf(s[3][0], s[3][1]), fmaxf(s[3][2], s[3][3]))));
    pmax = fmaxf(pmax, __shfl_xor(pmax, 16));
    pmax = fmaxf(pmax, __shfl_xor(pmax, 32));
    // defer-max (THR=8 in log2 units)
    if (__any(pmax > m + 8.0f)) {
      const float mn = fmaxf(m, pmax);
      const float al = EXP2(m - mn);
      m = mn;
      lsum *= al;
      float a4[4];
#pragma unroll
      for (int r = 0; r < 4; ++r) a4[r] = __shfl(al, (l & 48) | (kg * 4 + r));
#pragma unroll
      for (int df = 0; df < 4; ++df)
#pragma unroll
        for (int r = 0; r < 4; ++r) acc[df][r] *= a4[r];
    }
    // exp2 + per-lane sum + pack to bf16 + per-wave LDS (no barrier needed)
#pragma unroll
    for (int jf = 0; jf < 4; ++jf) {
      u32x2 wp;
#pragma unroll
      for (int rp = 0; rp < 2; ++rp) {
        const float e0 = EXP2(s[jf][rp * 2 + 0] - m);
        const float e1 = EXP2(s[jf][rp * 2 + 1] - m);
        lsum += e0 + e1;
        unsigned pk;
        asm("v_cvt_pk_bf16_f32 %0, %1, %2" : "=v"(pk) : "v"(e0), "v"(e1));
        wp[rp] = pk;
      }
      *(u32x2*)&ps[w][li * 72 + jf * 16 + kg * 4] = wp;
    }
    asm volatile("s_waitcnt lgkmcnt(0)" ::: "memory");
    __builtin_amdgcn_sched_barrier(0);
    // PV: A = P[q=li][kv], B = V^T rows from global (contiguous kv)
    const bf16x8 ap0 = *(const bf16x8*)&ps[w][li * 72 + kg * 8];
    const bf16x8 ap1 = *(const bf16x8*)&ps[w][li * 72 + 32 + kg * 8];
#pragma unroll
    for (int df = 0; df < 4; ++df) {
      const int dg = df * 16 + li;
      const bf16x8 bv0 = *(const bf16x8*)&vp[(size_t)dg * NKVP + kbase + kg * 8];
      const bf16x8 bv1 = *(const bf16x8*)&vp[(size_t)dg * NKVP + kbase + 32 + kg * 8];
      acc[df] = __builtin_amdgcn_mfma_f32_16x16x32_bf16(ap0, bv0, acc[df], 0, 0, 0);
      acc[df] = __builtin_amdgcn_mfma_f32_16x16x32_bf16(ap1, bv1, acc[df], 0, 0, 0);
    }
  }
  // final row sum of l (q=li), then gather to acc-row ownership (q=kg*4+r)
  lsum += __shfl_xor(lsum, 16);
  lsum += __shfl_xor(lsum, 32);
  float m4[4], l4[4];
#pragma unroll
  for (int r = 0; r < 4; ++r) {
    const int src = (l & 48) | (kg * 4 + r);
    m4[r] = __shfl(m, src);
    l4[r] = __shfl(lsum, src);
  }
  if (hf == 1) {
#pragma unroll
    for (int df = 0; df < 4; ++df)
#pragma unroll
      for (int r = 0; r < 4; ++r)
        accbuf[qsub][kg * 4 + r][df * 16 + li] = acc[df][r];
    if (kg == 0) { mlbuf[qsub][li][0] = m; mlbuf[qsub][li][1] = lsum; }
  }
  __syncthreads();
  if (hf == 0) {
    float f0[4], f1[4], rL[4];
#pragma unroll
    for (int r = 0; r < 4; ++r) {
      const float m1 = mlbuf[qsub][kg * 4 + r][0];
      const float l1 = mlbuf[qsub][kg * 4 + r][1];
      const float M = fmaxf(m4[r], m1);
      f0[r] = EXP2(m4[r] - M);
      f1[r] = EXP2(m1 - M);
      rL[r] = __builtin_amdgcn_rcpf(l4[r] * f0[r] + l1 * f1[r]);
    }
#pragma unroll
    for (int df = 0; df < 4; ++df)
#pragma unroll
      for (int r = 0; r < 4; ++r) {
        const float a1 = accbuf[qsub][kg * 4 + r][df * 16 + li];
        const float o = (acc[df][r] * f0[r] + a1 * f1[r]) * rL[r];
        aoB[((size_t)b * NPIX + qrow0 + kg * 4 + r) * HID + hh * DH + df * 16 + li] = f2b(o);
      }
  }
}

// ---------------- Kernel 6: out projection GEMM (bf16 MFMA) ---------------------
// out[b][o][p] = sum_c aoB[p][c] * wob[o][c];  grid (144, 8), block 256
__global__ __launch_bounds__(256) void k_outg(
    const u16* __restrict__ aoB, const u16* __restrict__ wob, float* __restrict__ out)
{
  const int t = threadIdx.x, w = t >> 6, l = t & 63, li = l & 15, kg = l >> 4;
  const int wm = w >> 1, wn = w & 1;
  const int m0 = blockIdx.x * 32 + wm * 16;
  const int n0 = blockIdx.y * 32 + wn * 16;
  const u16* ap = aoB + (size_t)(m0 + li) * HID + kg * 8;
  const u16* bp = wob + (size_t)(n0 + li) * HID + kg * 8;
  f32x4 acc = {0.f, 0.f, 0.f, 0.f};
#pragma unroll
  for (int ks = 0; ks < 16; ++ks) {
    const bf16x8 af = *(const bf16x8*)(ap + ks * 32);
    const bf16x8 bf = *(const bf16x8*)(bp + ks * 32);
    acc = __builtin_amdgcn_mfma_f32_16x16x32_bf16(af, bf, acc, 0, 0, 0);
  }
  const int bb = (m0 >= NPIX) ? 1 : 0;
  const int pl = m0 - bb * NPIX + kg * 4;
  const int o = n0 + li;
  *(f32x4*)&out[((size_t)(bb * CDIM + o)) * NPIX + pl] = acc;
}

extern "C" void kernel_launch(void* const* d_in, const int* in_sizes, int n_in,
                              void* d_out, int out_size, void* d_ws, size_t ws_size,
                              hipStream_t stream)
{
  const float* x      = (const float*)d_in[0];
  const float* gamma  = (const float*)d_in[1];
  const float* mem_kv = (const float*)d_in[2];
  const float* wqkv   = (const float*)d_in[3];
  const float* wout   = (const float*)d_in[4];
  float* out = (float*)d_out;
  char* ws = (char*)d_ws;
  const size_t XNT = (size_t)BATCH * NPIX * CDIM * sizeof(u16);        // 2,359,296
  const size_t WB  = (size_t)(WQKV_E + WOUT_E) * sizeof(u16);          // 1,048,576
  const size_t QB  = (size_t)BATCH * NHEAD * NPIX * DH * sizeof(u16);  // 4,718,592
  const size_t KB  = (size_t)BATCH * NHEAD * NKV  * DH * sizeof(u16);  // 4,726,784
  const size_t VTB = (size_t)BATCH * NHEAD * DH * NKVP * sizeof(u16);  // 4,849,664
  u16* xnT = (u16*)ws;
  u16* wb  = (u16*)(ws + XNT);
  u16* q   = (u16*)(ws + XNT + WB);
  u16* kk  = (u16*)(ws + XNT + WB + QB);
  u16* vT  = (u16*)(ws + XNT + WB + QB + KB);
  u16* aoB = (u16*)(ws + XNT + WB + QB + KB + VTB);  // + 4,718,592 -> ~22.4 MB

  k_prep_w<<<dim3(256), dim3(256), 0, stream>>>(wqkv, wout, wb);
  k_zeropad<<<dim3(64), dim3(256), 0, stream>>>(vT);
  k_fillmem<<<dim3(16), dim3(256), 0, stream>>>(mem_kv, kk, vT);
  k_norm<<<dim3(72), dim3(256), 0, stream>>>(x, gamma, xnT);
  k_qkv<<<dim3(72, 24), dim3(256), 0, stream>>>(xnT, wb, q, kk, vT);
  k_attn<<<dim3(36, 16), dim3(512), 0, stream>>>(q, kk, vT, aoB);
  k_outg<<<dim3(144, 8), dim3(256), 0, stream>>>(aoB, wb + WQKV_E, out);
}

// Round 4
// 129.123 us; speedup vs baseline: 2.0804x; 2.0804x over previous
//
#include <hip/hip_runtime.h>

#define BATCH 2
#define CDIM 256
#define NPIX 2304      // 48*48
#define NHEAD 8
#define DH 64
#define HID 512
#define NMEM 4
#define NKV 2308       // NMEM + NPIX
#define NKVP 2368      // NKV padded to multiple of 64 (zeroed pad)
#define QSCALE 0.125f  // 64^-0.5
#define LOG2E 1.4426950408889634f
#define WQKV_E 393216  // 1536*256
#define WOUT_E 131072  // 256*512

typedef float f32x4 __attribute__((ext_vector_type(4)));
typedef __bf16 bf16x8 __attribute__((ext_vector_type(8)));
typedef unsigned short u16;
typedef u16 u16x4 __attribute__((ext_vector_type(4)));
typedef u16 u16x8 __attribute__((ext_vector_type(8)));
typedef unsigned u32x2 __attribute__((ext_vector_type(2)));

#if __has_builtin(__builtin_amdgcn_exp2f)
#define EXP2(x) __builtin_amdgcn_exp2f(x)
#else
#define EXP2(x) exp2f(x)
#endif

static __device__ __forceinline__ u16 f2b(float f) {
  union { float f; unsigned u; } a; a.f = f;
  unsigned u = a.u;
  u += 0x7fffu + ((u >> 16) & 1u);   // RNE
  return (u16)(u >> 16);
}

// ---------------- Kernel 1: RMSNorm -> xn^T bf16 [b*p][c] -----------------------
// grid 72 (64 pixels/block), block 256
__global__ __launch_bounds__(256) void k_norm(
    const float* __restrict__ x, const float* __restrict__ gamma, u16* __restrict__ xnT)
{
  __shared__ float xs[64][257];
  __shared__ float red[4][64];
  __shared__ float rsh[64];
  __shared__ float g1[CDIM];
  const int t = threadIdx.x;
  const int bp0 = blockIdx.x * 64;
  const int bb = bp0 >= NPIX;
  const int p0 = bp0 - bb * NPIX;
  g1[t] = 1.0f + gamma[t];
  const float* xb = x + (size_t)bb * CDIM * NPIX;
  const int pq = (t & 15) * 4;
  const int cq0 = t >> 4;
#pragma unroll
  for (int it = 0; it < 16; ++it) {
    const int c = it * 16 + cq0;
    const f32x4 v = *(const f32x4*)&xb[(size_t)c * NPIX + p0 + pq];
    xs[pq + 0][c] = v[0]; xs[pq + 1][c] = v[1];
    xs[pq + 2][c] = v[2]; xs[pq + 3][c] = v[3];
  }
  __syncthreads();
  {
    const int p = t & 63, cg = t >> 6;
    float ssq = 0.f;
#pragma unroll
    for (int i = 0; i < 64; ++i) { const float v = xs[p][cg * 64 + i]; ssq += v * v; }
    red[cg][p] = ssq;
  }
  __syncthreads();
  if (t < 64) {
    const float s = red[0][t] + red[1][t] + red[2][t] + red[3][t];
    rsh[t] = 16.0f / fmaxf(sqrtf(s), 1e-12f);   // sqrt(CDIM)=16
  }
  __syncthreads();
#pragma unroll
  for (int it = 0; it < 8; ++it) {
    const int idx = it * 256 + t;
    const int pp = idx >> 5, c0 = (idx & 31) * 8;
    const float rs = rsh[pp];
    u16x8 o;
#pragma unroll
    for (int e = 0; e < 8; ++e) o[e] = f2b(xs[pp][c0 + e] * rs * g1[c0 + e]);
    *(u16x8*)&xnT[(size_t)(bp0 + pp) * CDIM + c0] = o;
  }
}

// ---------------- Kernel 2: cast weights to bf16 (QSCALE*log2e into q rows) -----
// grid 256, block 256; wb = [wqkv bf16 (1536x256) | wout bf16 (256x512)]
__global__ __launch_bounds__(256) void k_prep_w(
    const float* __restrict__ wqkv, const float* __restrict__ wout, u16* __restrict__ wb)
{
  const int i0 = (blockIdx.x * 256 + threadIdx.x) * 8;
  const float* src;
  float sc = 1.0f;
  if (i0 < WQKV_E) { src = wqkv + i0; if ((i0 >> 8) < 512) sc = QSCALE * LOG2E; }
  else             { src = wout + (i0 - WQKV_E); }
  const f32x4 a = *(const f32x4*)src;
  const f32x4 b = *(const f32x4*)(src + 4);
  u16x8 o;
#pragma unroll
  for (int e = 0; e < 4; ++e) { o[e] = f2b(a[e] * sc); o[e + 4] = f2b(b[e] * sc); }
  *(u16x8*)&wb[i0] = o;
}

// ---------------- Kernel 3a: zero vT tail (kv 2304..2367) -----------------------
__global__ __launch_bounds__(256) void k_zeropad(u16* __restrict__ vT)
{
  const int gid = blockIdx.x * 256 + threadIdx.x;     // 0..16383
  const int row = gid >> 4;                            // bh*64+d
  const int c0 = (gid & 15) * 4 + 2304;
  u16x4 z = {0, 0, 0, 0};
  *(u16x4*)&vT[(size_t)row * NKVP + c0] = z;
}

// ---------------- Kernel 3b: fill memory kv tokens (kv rows 0..3) ---------------
__global__ __launch_bounds__(256) void k_fillmem(const float* __restrict__ mem_kv,
                                                 u16* __restrict__ kk, u16* __restrict__ vT)
{
  const int idx = blockIdx.x * 256 + threadIdx.x;  // 0..4095 = b,h,m,d
  const int d = idx & 63;
  const int m = (idx >> 6) & 3;
  const int h = (idx >> 8) & 7;
  const int b = idx >> 11;
  const float mk = mem_kv[((size_t)h * NMEM + m) * DH + d];
  const float mv = mem_kv[(((size_t)NHEAD + h) * NMEM + m) * DH + d];
  kk[(((size_t)(b * NHEAD + h)) * NKV + m) * DH + d] = f2b(mk);
  vT[(((size_t)(b * NHEAD + h)) * DH + d) * NKVP + m] = f2b(mv);
}

// ---------------- Kernel 4: QKV projection GEMM (bf16 MFMA) ---------------------
// C[p][o] = sum_c xnT[p][c] * wb[o][c];  grid (72, 24), block 256 (4 waves x 16 rows)
__global__ __launch_bounds__(256) void k_qkv(
    const u16* __restrict__ xnT, const u16* __restrict__ wb,
    u16* __restrict__ q, u16* __restrict__ kk, u16* __restrict__ vT)
{
  const int t = threadIdx.x, w = t >> 6, l = t & 63, li = l & 15, kg = l >> 4;
  const int m0 = blockIdx.x * 64 + w * 16;
  const int n0 = blockIdx.y * 64;
  const u16* ap = xnT + (size_t)(m0 + li) * CDIM + kg * 8;
  f32x4 acc[4];
#pragma unroll
  for (int cf = 0; cf < 4; ++cf) { f32x4 z = {0.f,0.f,0.f,0.f}; acc[cf] = z; }
#pragma unroll
  for (int ks = 0; ks < 8; ++ks) {
    const bf16x8 af = *(const bf16x8*)(ap + ks * 32);
#pragma unroll
    for (int cf = 0; cf < 4; ++cf) {
      const int o = n0 + cf * 16 + li;
      const bf16x8 bfr = *(const bf16x8*)(wb + (size_t)o * CDIM + ks * 32 + kg * 8);
      acc[cf] = __builtin_amdgcn_mfma_f32_16x16x32_bf16(af, bfr, acc[cf], 0, 0, 0);
    }
  }
  const int bb = (m0 >= NPIX) ? 1 : 0;
  const int plbase = m0 - bb * NPIX + kg * 4;
#pragma unroll
  for (int cf = 0; cf < 4; ++cf) {
    const int o0f = n0 + cf * 16;          // uniform over lanes
    const int r = o0f >> 9, oo = o0f & 511, h = oo >> 6, d = (oo & 63) + li;
    if (r == 0) {
      u16* base = q + ((size_t)(bb * NHEAD + h) * NPIX + plbase) * DH + d;
#pragma unroll
      for (int rr = 0; rr < 4; ++rr) base[(size_t)rr * DH] = f2b(acc[cf][rr]);
    } else if (r == 1) {
      u16* base = kk + ((size_t)(bb * NHEAD + h) * NKV + NMEM + plbase) * DH + d;
#pragma unroll
      for (int rr = 0; rr < 4; ++rr) base[(size_t)rr * DH] = f2b(acc[cf][rr]);
    } else {
      u16x4 pk;
#pragma unroll
      for (int rr = 0; rr < 4; ++rr) pk[rr] = f2b(acc[cf][rr]);
      *(u16x4*)&vT[(((size_t)(bb * NHEAD + h)) * DH + d) * NKVP + NMEM + plbase] = pk;
    }
  }
}

// ---------------- Kernel 5: flash attention --------------------------------------
// grid 576 (XCD-swizzled 1D); block 256 = 4 waves x 16 q-rows; KT = 64
// K+V staged in swizzled LDS (shared by all waves), reg-prefetch 1 tile ahead.
__global__ __launch_bounds__(256) void k_attn(
    const u16* __restrict__ q, const u16* __restrict__ kk, const u16* __restrict__ vT,
    u16* __restrict__ aoB)
{
  __shared__ __align__(16) u16 kbuf[64 * 64];    // [kv][d], col ^= (row&7)*8
  __shared__ __align__(16) u16 vbuf[64 * 64];    // [d][kv], col ^= (row&7)*8
  __shared__ __align__(16) u16 ps[4][16 * 72];   // per-wave P (bf16)
  const int t = threadIdx.x;
  const int w = t >> 6, l = t & 63;
  const int li = l & 15, kg = l >> 4;
  // XCD-aware decode: id&7 -> XCD; each XCD owns 2 heads (K/V 1.18MB, L2-resident)
  const int id = blockIdx.x;
  const int xcd = id & 7, slot = id >> 3;        // slot 0..71
  const int yl = (slot >= 36) ? 1 : 0;
  const int xq = slot - yl * 36;
  const int bh = xcd * 2 + yl;
  const int b = bh >> 3, hh = bh & 7;
  const int qrow0 = xq * 64 + w * 16;
  const u16* qp = q + ((size_t)bh * NPIX + qrow0) * DH;
  const u16* kp = kk + (size_t)bh * NKV * DH;
  const u16* vp = vT + (size_t)bh * DH * NKVP;

  // Q B-fragment (persistent): lane (li,kg) holds Q[q=li][d=kg*8+e]
  const bf16x8 bq0 = *(const bf16x8*)&qp[li * DH + kg * 8];
  const bf16x8 bq1 = *(const bf16x8*)&qp[li * DH + 32 + kg * 8];

  // staging geometry: thread t covers rows srow, srow+32 at 16B column scol*2
  const int srow = t >> 3;                 // 0..31
  const int scol = (t & 7) * 8;            // u16 units
  const int ssw = (srow & 7) * 8;          // same for srow+32
  const size_t vb0 = (size_t)srow * NKVP + scol;
  const size_t vb1 = (size_t)(srow + 32) * NKVP + scol;

  f32x4 acc[4];
#pragma unroll
  for (int df = 0; df < 4; ++df) { f32x4 z = {0.f,0.f,0.f,0.f}; acc[df] = z; }
  float m = -1e30f, lsum = 0.f;   // for q = li (uniform across kg)

  u16x8 rk0, rk1, rv0, rv1;
  // prologue: load tile 0 into regs
  rk0 = *(const u16x8*)&kp[(size_t)srow * DH + scol];
  rk1 = *(const u16x8*)&kp[(size_t)(srow + 32) * DH + scol];
  rv0 = *(const u16x8*)&vp[vb0];
  rv1 = *(const u16x8*)&vp[vb1];

  const int NT = 37;
  for (int tile = 0; tile < NT; ++tile) {
    const int kbase = tile * 64;
    __syncthreads();   // all waves done reading kbuf/vbuf from previous tile
    *(u16x8*)&kbuf[srow * 64 + (scol ^ ssw)] = rk0;
    *(u16x8*)&kbuf[(srow + 32) * 64 + (scol ^ ssw)] = rk1;
    *(u16x8*)&vbuf[srow * 64 + (scol ^ ssw)] = rv0;
    *(u16x8*)&vbuf[(srow + 32) * 64 + (scol ^ ssw)] = rv1;
    if (tile + 1 < NT) {   // prefetch next tile; latency hides under compute below
      const int nb = kbase + 64;
      int kr0 = nb + srow;      if (kr0 > NKV - 1) kr0 = NKV - 1;
      int kr1 = nb + srow + 32; if (kr1 > NKV - 1) kr1 = NKV - 1;
      rk0 = *(const u16x8*)&kp[(size_t)kr0 * DH + scol];
      rk1 = *(const u16x8*)&kp[(size_t)kr1 * DH + scol];
      rv0 = *(const u16x8*)&vp[vb0 + nb];
      rv1 = *(const u16x8*)&vp[vb1 + nb];
    }
    __syncthreads();   // kbuf/vbuf ready
    const bool lastt = (kbase + 64 > NKV);
    // S^T = K . Q^T : A = K rows from LDS, B = Q. C: lane holds kv=kg*4+r, q=li.
    f32x4 s[4];
#pragma unroll
    for (int jf = 0; jf < 4; ++jf) {
      const int row = jf * 16 + li;
      const int rsw = (row & 7) * 8;
      const bf16x8 ak0 = *(const bf16x8*)&kbuf[row * 64 + ((kg * 8) ^ rsw)];
      const bf16x8 ak1 = *(const bf16x8*)&kbuf[row * 64 + ((32 + kg * 8) ^ rsw)];
      f32x4 sf = {0.f, 0.f, 0.f, 0.f};
      sf = __builtin_amdgcn_mfma_f32_16x16x32_bf16(ak0, bq0, sf, 0, 0, 0);
      sf = __builtin_amdgcn_mfma_f32_16x16x32_bf16(ak1, bq1, sf, 0, 0, 0);
      s[jf] = sf;
    }
    if (lastt) {
#pragma unroll
      for (int jf = 0; jf < 4; ++jf)
#pragma unroll
        for (int r = 0; r < 4; ++r)
          if (kbase + jf * 16 + kg * 4 + r >= NKV) s[jf][r] = -1e30f;
    }
    // row max (row = q = li): local 16-value tree + 2 shfls
    float pmax = fmaxf(fmaxf(fmaxf(s[0][0], s[0][1]), fmaxf(s[0][2], s[0][3])),
                       fmaxf(fmaxf(s[1][0], s[1][1]), fmaxf(s[1][2], s[1][3])));
    pmax = fmaxf(pmax, fmaxf(fmaxf(fmaxf(s[2][0], s[2][1]), fmaxf(s[2][2], s[2][3])),
                             fmaxf(fmaxf(s[3][0], s[3][1]), fmaxf(s[3][2], s[3][3]))));
    pmax = fmaxf(pmax, __shfl_xor(pmax, 16));
    pmax = fmaxf(pmax, __shfl_xor(pmax, 32));
    // defer-max (THR=8 in log2 units)
    if (__any(pmax > m + 8.0f)) {
      const float mn = fmaxf(m, pmax);
      const float al = EXP2(m - mn);
      m = mn;
      lsum *= al;
      float a4[4];
#pragma unroll
      for (int r = 0; r < 4; ++r) a4[r] = __shfl(al, (l & 48) | (kg * 4 + r));
#pragma unroll
      for (int df = 0; df < 4; ++df)
#pragma unroll
        for (int r = 0; r < 4; ++r) acc[df][r] *= a4[r];
    }
    // exp2 + per-lane sum + pack to bf16 + per-wave LDS (no barrier needed)
#pragma unroll
    for (int jf = 0; jf < 4; ++jf) {
      u32x2 wp;
#pragma unroll
      for (int rp = 0; rp < 2; ++rp) {
        const float e0 = EXP2(s[jf][rp * 2 + 0] - m);
        const float e1 = EXP2(s[jf][rp * 2 + 1] - m);
        lsum += e0 + e1;
        unsigned pk;
        asm("v_cvt_pk_bf16_f32 %0, %1, %2" : "=v"(pk) : "v"(e0), "v"(e1));
        wp[rp] = pk;
      }
      *(u32x2*)&ps[w][li * 72 + jf * 16 + kg * 4] = wp;
    }
    asm volatile("s_waitcnt lgkmcnt(0)" ::: "memory");
    __builtin_amdgcn_sched_barrier(0);
    // PV: A = P[q=li][kv], B = V^T rows from swizzled LDS
    const bf16x8 ap0 = *(const bf16x8*)&ps[w][li * 72 + kg * 8];
    const bf16x8 ap1 = *(const bf16x8*)&ps[w][li * 72 + 32 + kg * 8];
#pragma unroll
    for (int df = 0; df < 4; ++df) {
      const int row = df * 16 + li;
      const int rsw = (row & 7) * 8;
      const bf16x8 bv0 = *(const bf16x8*)&vbuf[row * 64 + ((kg * 8) ^ rsw)];
      const bf16x8 bv1 = *(const bf16x8*)&vbuf[row * 64 + ((32 + kg * 8) ^ rsw)];
      acc[df] = __builtin_amdgcn_mfma_f32_16x16x32_bf16(ap0, bv0, acc[df], 0, 0, 0);
      acc[df] = __builtin_amdgcn_mfma_f32_16x16x32_bf16(ap1, bv1, acc[df], 0, 0, 0);
    }
  }
  // epilogue: final l per q-row, gather to acc-row ownership (q=kg*4+r), write
  lsum += __shfl_xor(lsum, 16);
  lsum += __shfl_xor(lsum, 32);
  float rL[4];
#pragma unroll
  for (int r = 0; r < 4; ++r) {
    const float l4 = __shfl(lsum, (l & 48) | (kg * 4 + r));
    rL[r] = __builtin_amdgcn_rcpf(l4);
  }
#pragma unroll
  for (int df = 0; df < 4; ++df)
#pragma unroll
    for (int r = 0; r < 4; ++r) {
      const int p = qrow0 + kg * 4 + r;
      aoB[((size_t)b * NPIX + p) * HID + hh * DH + df * 16 + li] = f2b(acc[df][r] * rL[r]);
    }
}

// ---------------- Kernel 6: out projection GEMM (bf16 MFMA) ---------------------
// out[b][o][p] = sum_c aoB[p][c] * wob[o][c];  grid (144, 8), block 256
__global__ __launch_bounds__(256) void k_outg(
    const u16* __restrict__ aoB, const u16* __restrict__ wob, float* __restrict__ out)
{
  const int t = threadIdx.x, w = t >> 6, l = t & 63, li = l & 15, kg = l >> 4;
  const int wm = w >> 1, wn = w & 1;
  const int m0 = blockIdx.x * 32 + wm * 16;
  const int n0 = blockIdx.y * 32 + wn * 16;
  const u16* ap = aoB + (size_t)(m0 + li) * HID + kg * 8;
  const u16* bp = wob + (size_t)(n0 + li) * HID + kg * 8;
  f32x4 acc = {0.f, 0.f, 0.f, 0.f};
#pragma unroll
  for (int ks = 0; ks < 16; ++ks) {
    const bf16x8 af = *(const bf16x8*)(ap + ks * 32);
    const bf16x8 bf = *(const bf16x8*)(bp + ks * 32);
    acc = __builtin_amdgcn_mfma_f32_16x16x32_bf16(af, bf, acc, 0, 0, 0);
  }
  const int bb = (m0 >= NPIX) ? 1 : 0;
  const int pl = m0 - bb * NPIX + kg * 4;
  const int o = n0 + li;
  *(f32x4*)&out[((size_t)(bb * CDIM + o)) * NPIX + pl] = acc;
}

extern "C" void kernel_launch(void* const* d_in, const int* in_sizes, int n_in,
                              void* d_out, int out_size, void* d_ws, size_t ws_size,
                              hipStream_t stream)
{
  const float* x      = (const float*)d_in[0];
  const float* gamma  = (const float*)d_in[1];
  const float* mem_kv = (const float*)d_in[2];
  const float* wqkv   = (const float*)d_in[3];
  const float* wout   = (const float*)d_in[4];
  float* out = (float*)d_out;
  char* ws = (char*)d_ws;
  const size_t XNT = (size_t)BATCH * NPIX * CDIM * sizeof(u16);        // 2,359,296
  const size_t WB  = (size_t)(WQKV_E + WOUT_E) * sizeof(u16);          // 1,048,576
  const size_t QB  = (size_t)BATCH * NHEAD * NPIX * DH * sizeof(u16);  // 4,718,592
  const size_t KB  = (size_t)BATCH * NHEAD * NKV  * DH * sizeof(u16);  // 4,726,784
  const size_t VTB = (size_t)BATCH * NHEAD * DH * NKVP * sizeof(u16);  // 4,849,664
  u16* xnT = (u16*)ws;
  u16* wb  = (u16*)(ws + XNT);
  u16* q   = (u16*)(ws + XNT + WB);
  u16* kk  = (u16*)(ws + XNT + WB + QB);
  u16* vT  = (u16*)(ws + XNT + WB + QB + KB);
  u16* aoB = (u16*)(ws + XNT + WB + QB + KB + VTB);  // + 4,718,592 -> ~22.4 MB

  k_prep_w<<<dim3(256), dim3(256), 0, stream>>>(wqkv, wout, wb);
  k_zeropad<<<dim3(64), dim3(256), 0, stream>>>(vT);
  k_fillmem<<<dim3(16), dim3(256), 0, stream>>>(mem_kv, kk, vT);
  k_norm<<<dim3(72), dim3(256), 0, stream>>>(x, gamma, xnT);
  k_qkv<<<dim3(72, 24), dim3(256), 0, stream>>>(xnT, wb, q, kk, vT);
  k_attn<<<dim3(576), dim3(256), 0, stream>>>(q, kk, vT, aoB);
  k_outg<<<dim3(144, 8), dim3(256), 0, stream>>>(aoB, wb + WQKV_E, out);
}

// Round 5
// 104.427 us; speedup vs baseline: 2.5724x; 1.2365x over previous
//
#include <hip/hip_runtime.h>

#define BATCH 2
#define CDIM 256
#define NPIX 2304      // 48*48
#define NHEAD 8
#define DH 64
#define HID 512
#define NMEM 4
#define NKV 2308       // NMEM + NPIX
#define NKVP 2368      // NKV padded to multiple of 64 (zeroed pad)
#define QSCALE 0.125f  // 64^-0.5
#define LOG2E 1.4426950408889634f
#define WQKV_E 393216  // 1536*256
#define WOUT_E 131072  // 256*512
#define KVSPLIT 1216   // 19 tiles * 64 for half 0; half 1 covers 1216..2367

typedef float f32x4 __attribute__((ext_vector_type(4)));
typedef __bf16 bf16x8 __attribute__((ext_vector_type(8)));
typedef unsigned short u16;
typedef u16 u16x4 __attribute__((ext_vector_type(4)));
typedef u16 u16x8 __attribute__((ext_vector_type(8)));
typedef unsigned u32x2 __attribute__((ext_vector_type(2)));

#if __has_builtin(__builtin_amdgcn_exp2f)
#define EXP2(x) __builtin_amdgcn_exp2f(x)
#else
#define EXP2(x) exp2f(x)
#endif

static __device__ __forceinline__ u16 f2b(float f) {
  union { float f; unsigned u; } a; a.f = f;
  unsigned u = a.u;
  u += 0x7fffu + ((u >> 16) & 1u);   // RNE
  return (u16)(u >> 16);
}

// ---------------- Kernel 1: merged prep --------------------------------------
// blocks 0..255: wb = bf16(wqkv * g1 [* QSCALE*LOG2E on q rows]) | bf16(wout)
// blocks 256..271: mem kv tokens -> kk rows 0..3, vT cols 0..3
// blocks 272..335: zero vT tail cols 2304..2367
__global__ __launch_bounds__(256) void k_prep(
    const float* __restrict__ wqkv, const float* __restrict__ wout,
    const float* __restrict__ gamma, const float* __restrict__ mem_kv,
    u16* __restrict__ wb, u16* __restrict__ kk, u16* __restrict__ vT)
{
  const int blk = blockIdx.x, t = threadIdx.x;
  if (blk < 256) {
    const int i0 = (blk * 256 + t) * 8;
    u16x8 o;
    if (i0 < WQKV_E) {
      const float sc = ((i0 >> 8) < 512) ? QSCALE * LOG2E : 1.0f;
      const int c0 = i0 & 255;
      const f32x4 a = *(const f32x4*)&wqkv[i0];
      const f32x4 b = *(const f32x4*)&wqkv[i0 + 4];
      const f32x4 g0 = *(const f32x4*)&gamma[c0];
      const f32x4 g1 = *(const f32x4*)&gamma[c0 + 4];
#pragma unroll
      for (int e = 0; e < 4; ++e) {
        o[e]     = f2b(a[e] * sc * (1.0f + g0[e]));
        o[e + 4] = f2b(b[e] * sc * (1.0f + g1[e]));
      }
    } else {
      const f32x4 a = *(const f32x4*)&wout[i0 - WQKV_E];
      const f32x4 b = *(const f32x4*)&wout[i0 - WQKV_E + 4];
#pragma unroll
      for (int e = 0; e < 4; ++e) { o[e] = f2b(a[e]); o[e + 4] = f2b(b[e]); }
    }
    *(u16x8*)&wb[i0] = o;
  } else if (blk < 272) {
    const int idx = (blk - 256) * 256 + t;   // 0..4095 = b,h,m,d
    const int d = idx & 63;
    const int m = (idx >> 6) & 3;
    const int h = (idx >> 8) & 7;
    const int b = idx >> 11;
    const float mk = mem_kv[((size_t)h * NMEM + m) * DH + d];
    const float mv = mem_kv[(((size_t)NHEAD + h) * NMEM + m) * DH + d];
    kk[(((size_t)(b * NHEAD + h)) * NKV + m) * DH + d] = f2b(mk);
    vT[(((size_t)(b * NHEAD + h)) * DH + d) * NKVP + m] = f2b(mv);
  } else {
    const int gid = (blk - 272) * 256 + t;   // 0..16383
    const int row = gid >> 4;                 // bh*64+d
    const int c0 = (gid & 15) * 4 + 2304;
    u16x4 z = {0, 0, 0, 0};
    *(u16x4*)&vT[(size_t)row * NKVP + c0] = z;
  }
}

// ---------------- Kernel 2: RMSNorm -> xn^T bf16 [b*p][c] (gamma in weights) ----
// grid 288 (16 pixels/block), block 256
__global__ __launch_bounds__(256) void k_norm(
    const float* __restrict__ x, u16* __restrict__ xnT)
{
  __shared__ float xs[16 * 261];
  __shared__ float red[16][17];
  __shared__ float rsh[16];
  const int t = threadIdx.x;
  const int blk = blockIdx.x;
  const int b = blk / 144;
  const int p0 = (blk % 144) * 16;
  const int px = t & 15, cg = t >> 4;
  const float* xb = x + (size_t)b * CDIM * NPIX + p0 + px;
  float ssq = 0.f;
#pragma unroll
  for (int i = 0; i < 16; ++i) {
    const int c = cg * 16 + i;
    const float v = xb[(size_t)c * NPIX];
    xs[px * 261 + c] = v;
    ssq += v * v;
  }
  red[px][cg] = ssq;
  __syncthreads();
  if (t < 16) {
    float s = 0.f;
#pragma unroll
    for (int i = 0; i < 16; ++i) s += red[t][i];
    rsh[t] = 16.0f / fmaxf(sqrtf(s), 1e-12f);   // sqrt(CDIM)=16
  }
  __syncthreads();
  {
    const int pp = t >> 4, c0 = (t & 15) * 16;
    const float rs = rsh[pp];
    u16x8 o0, o1;
#pragma unroll
    for (int e = 0; e < 8; ++e) {
      o0[e] = f2b(xs[pp * 261 + c0 + e] * rs);
      o1[e] = f2b(xs[pp * 261 + c0 + 8 + e] * rs);
    }
    u16* dst = &xnT[(size_t)(b * NPIX + p0 + pp) * CDIM + c0];
    *(u16x8*)dst = o0;
    *(u16x8*)(dst + 8) = o1;
  }
}

// ---------------- Kernel 3: QKV projection GEMM (bf16 MFMA, B staged in LDS) ----
// C[p][o] = sum_c xnT[p][c] * wb[o][c];  grid (72, 24), block 256 (4 waves x 16 rows)
__global__ __launch_bounds__(256) void k_qkv(
    const u16* __restrict__ xnT, const u16* __restrict__ wb,
    u16* __restrict__ q, u16* __restrict__ kk, u16* __restrict__ vT)
{
  __shared__ __align__(16) u16 bs[64 * 256];   // [row][col ^ (row&7)*8]
  const int t = threadIdx.x, w = t >> 6, l = t & 63, li = l & 15, kg = l >> 4;
  const int m0 = blockIdx.x * 64 + w * 16;
  const int n0 = blockIdx.y * 64;
  // stage B tile (64 rows x 256 c) swizzled
  {
    const int brow = t >> 2, bcs = (t & 3) * 64;
    const int bsw = (brow & 7) * 8;
    const u16* wsrc = wb + (size_t)(n0 + brow) * CDIM + bcs;
#pragma unroll
    for (int j = 0; j < 8; ++j) {
      const u16x8 v = *(const u16x8*)&wsrc[j * 8];
      *(u16x8*)&bs[brow * 256 + ((bcs + j * 8) ^ bsw)] = v;
    }
  }
  const u16* ap = xnT + (size_t)(m0 + li) * CDIM + kg * 8;
  const int lsw = (li & 7) * 8;
  f32x4 acc[4];
#pragma unroll
  for (int cf = 0; cf < 4; ++cf) { f32x4 z = {0.f,0.f,0.f,0.f}; acc[cf] = z; }
  __syncthreads();
#pragma unroll
  for (int ks = 0; ks < 8; ++ks) {
    const bf16x8 af = *(const bf16x8*)(ap + ks * 32);
#pragma unroll
    for (int cf = 0; cf < 4; ++cf) {
      const int row = cf * 16 + li;
      const bf16x8 bfr = *(const bf16x8*)&bs[row * 256 + ((ks * 32 + kg * 8) ^ lsw)];
      acc[cf] = __builtin_amdgcn_mfma_f32_16x16x32_bf16(af, bfr, acc[cf], 0, 0, 0);
    }
  }
  const int bb = (m0 >= NPIX) ? 1 : 0;
  const int plbase = m0 - bb * NPIX + kg * 4;
#pragma unroll
  for (int cf = 0; cf < 4; ++cf) {
    const int o0f = n0 + cf * 16;          // uniform over lanes
    const int r = o0f >> 9, oo = o0f & 511, h = oo >> 6, d = (oo & 63) + li;
    if (r == 0) {
      u16* base = q + ((size_t)(bb * NHEAD + h) * NPIX + plbase) * DH + d;
#pragma unroll
      for (int rr = 0; rr < 4; ++rr) base[(size_t)rr * DH] = f2b(acc[cf][rr]);
    } else if (r == 1) {
      u16* base = kk + ((size_t)(bb * NHEAD + h) * NKV + NMEM + plbase) * DH + d;
#pragma unroll
      for (int rr = 0; rr < 4; ++rr) base[(size_t)rr * DH] = f2b(acc[cf][rr]);
    } else {
      u16x4 pk;
#pragma unroll
      for (int rr = 0; rr < 4; ++rr) pk[rr] = f2b(acc[cf][rr]);
      *(u16x4*)&vT[(((size_t)(bb * NHEAD + h)) * DH + d) * NKVP + NMEM + plbase] = pk;
    }
  }
}

// ---------------- Kernel 4: flash attention, in-block KV split ------------------
// grid 576 (XCD-swizzled); block 512 = 8 waves: (qsub 0..3) x (kv-half 0..1)
// Each half stages its own K/V LDS tiles; m/l/acc combined in LDS at the end.
__global__ __launch_bounds__(512) void k_attn(
    const u16* __restrict__ q, const u16* __restrict__ kk, const u16* __restrict__ vT,
    u16* __restrict__ aoB)
{
  __shared__ __align__(16) char smem[51200];
  u16* kbuf = (u16*)smem;                    // [2][64*64], swizzled
  u16* vbuf = (u16*)(smem + 16384);          // [2][64*64], swizzled
  u16* ps   = (u16*)(smem + 32768);          // [8][16*72]
  float* accbuf = (float*)smem;              // epilogue overlay [4][16][67]
  float* mlbuf  = (float*)(smem + 17152);    // epilogue overlay [4][16][2]
  const int t = threadIdx.x;
  const int w = t >> 6, l = t & 63;
  const int qsub = w & 3, hf = w >> 2;
  const int li = l & 15, kg = l >> 4;
  // XCD-aware decode: id&7 -> XCD; each XCD owns 2 heads (K/V L2-resident)
  const int id = blockIdx.x;
  const int xcd = id & 7, slot = id >> 3;    // slot 0..71
  const int yl = (slot >= 36) ? 1 : 0;
  const int xq = slot - yl * 36;
  const int bh = xcd * 2 + yl;
  const int b = bh >> 3, hh = bh & 7;
  const int qrow0 = xq * 64 + qsub * 16;
  const u16* qp = q + ((size_t)bh * NPIX + qrow0) * DH;
  const u16* kp = kk + (size_t)bh * NKV * DH;
  const u16* vp = vT + (size_t)bh * DH * NKVP;

  // Q B-fragment (persistent): lane (li,kg) holds Q[q=li][d=kg*8+e]
  const bf16x8 bq0 = *(const bf16x8*)&qp[li * DH + kg * 8];
  const bf16x8 bq1 = *(const bf16x8*)&qp[li * DH + 32 + kg * 8];

  // staging geometry: threads t<256 stage half 0, t>=256 stage half 1
  const int hft = t >> 8;
  const int tt = t & 255;
  const int srow = tt >> 3;                  // 0..31
  const int scol = (tt & 7) * 8;             // u16 units
  const int ssw = (srow & 7) * 8;
  const int sbase = hft * KVSPLIT;
  u16* kdst0 = &kbuf[hft * 4096 + srow * 64 + (scol ^ ssw)];
  u16* kdst1 = &kbuf[hft * 4096 + (srow + 32) * 64 + (scol ^ ssw)];
  u16* vdst0 = &vbuf[hft * 4096 + srow * 64 + (scol ^ ssw)];
  u16* vdst1 = &vbuf[hft * 4096 + (srow + 32) * 64 + (scol ^ ssw)];

  f32x4 acc[4];
#pragma unroll
  for (int df = 0; df < 4; ++df) { f32x4 z = {0.f,0.f,0.f,0.f}; acc[df] = z; }
  float m = -1e30f, lsum = 0.f;   // for q = li (uniform across kg)
  const int cbase0 = hf * KVSPLIT;

  u16x8 rk0, rk1, rv0, rv1;
  // prologue: load tile 0 of this half into regs
  rk0 = *(const u16x8*)&kp[(size_t)(sbase + srow) * DH + scol];
  rk1 = *(const u16x8*)&kp[(size_t)(sbase + srow + 32) * DH + scol];
  rv0 = *(const u16x8*)&vp[(size_t)srow * NKVP + sbase + scol];
  rv1 = *(const u16x8*)&vp[(size_t)(srow + 32) * NKVP + sbase + scol];

  const int NT = 19;
  for (int i = 0; i < NT; ++i) {
    __syncthreads();   // all waves done reading kbuf/vbuf from previous tile
    *(u16x8*)kdst0 = rk0;
    *(u16x8*)kdst1 = rk1;
    *(u16x8*)vdst0 = rv0;
    *(u16x8*)vdst1 = rv1;
    if (i + 1 < NT) {
      int nb = sbase + (i + 1) * 64;
      int snb = (nb > NKVP - 64) ? (NKVP - 64) : nb;   // V clamp (hf=1 last iter)
      int kr0 = nb + srow;      if (kr0 > NKV - 1) kr0 = NKV - 1;
      int kr1 = nb + srow + 32; if (kr1 > NKV - 1) kr1 = NKV - 1;
      rk0 = *(const u16x8*)&kp[(size_t)kr0 * DH + scol];
      rk1 = *(const u16x8*)&kp[(size_t)kr1 * DH + scol];
      rv0 = *(const u16x8*)&vp[(size_t)srow * NKVP + snb + scol];
      rv1 = *(const u16x8*)&vp[(size_t)(srow + 32) * NKVP + snb + scol];
    }
    __syncthreads();   // kbuf/vbuf ready
    const int kbase = cbase0 + i * 64;
    if (kbase < NKV) {     // wave-uniform; hf=1 skips its dummy 19th tile
      const bool lastt = (kbase + 64 > NKV);
      const u16* kb = &kbuf[hf * 4096];
      const u16* vb = &vbuf[hf * 4096];
      // S^T = K . Q^T : lane holds kv=kg*4+r, q=li
      f32x4 s[4];
#pragma unroll
      for (int jf = 0; jf < 4; ++jf) {
        const int row = jf * 16 + li;
        const int rsw = (row & 7) * 8;
        const bf16x8 ak0 = *(const bf16x8*)&kb[row * 64 + ((kg * 8) ^ rsw)];
        const bf16x8 ak1 = *(const bf16x8*)&kb[row * 64 + ((32 + kg * 8) ^ rsw)];
        f32x4 sf = {0.f, 0.f, 0.f, 0.f};
        sf = __builtin_amdgcn_mfma_f32_16x16x32_bf16(ak0, bq0, sf, 0, 0, 0);
        sf = __builtin_amdgcn_mfma_f32_16x16x32_bf16(ak1, bq1, sf, 0, 0, 0);
        s[jf] = sf;
      }
      if (lastt) {
#pragma unroll
        for (int jf = 0; jf < 4; ++jf)
#pragma unroll
          for (int r = 0; r < 4; ++r)
            if (kbase + jf * 16 + kg * 4 + r >= NKV) s[jf][r] = -1e30f;
      }
      // row max (row = q = li)
      float pmax = fmaxf(fmaxf(fmaxf(s[0][0], s[0][1]), fmaxf(s[0][2], s[0][3])),
                         fmaxf(fmaxf(s[1][0], s[1][1]), fmaxf(s[1][2], s[1][3])));
      pmax = fmaxf(pmax, fmaxf(fmaxf(fmaxf(s[2][0], s[2][1]), fmaxf(s[2][2], s[2][3])),
                               fmaxf(fmaxf(s[3][0], s[3][1]), fmaxf(s[3][2], s[3][3]))));
      pmax = fmaxf(pmax, __shfl_xor(pmax, 16));
      pmax = fmaxf(pmax, __shfl_xor(pmax, 32));
      // defer-max (THR=8 in log2 units)
      if (__any(pmax > m + 8.0f)) {
        const float mn = fmaxf(m, pmax);
        const float al = EXP2(m - mn);
        m = mn;
        lsum *= al;
        float a4[4];
#pragma unroll
        for (int r = 0; r < 4; ++r) a4[r] = __shfl(al, (l & 48) | (kg * 4 + r));
#pragma unroll
        for (int df = 0; df < 4; ++df)
#pragma unroll
          for (int r = 0; r < 4; ++r) acc[df][r] *= a4[r];
      }
      // exp2 + per-lane sum + pack to bf16 + per-wave LDS
#pragma unroll
      for (int jf = 0; jf < 4; ++jf) {
        u32x2 wp;
#pragma unroll
        for (int rp = 0; rp < 2; ++rp) {
          const float e0 = EXP2(s[jf][rp * 2 + 0] - m);
          const float e1 = EXP2(s[jf][rp * 2 + 1] - m);
          lsum += e0 + e1;
          unsigned pk;
          asm("v_cvt_pk_bf16_f32 %0, %1, %2" : "=v"(pk) : "v"(e0), "v"(e1));
          wp[rp] = pk;
        }
        *(u32x2*)&ps[w * 1152 + li * 72 + jf * 16 + kg * 4] = wp;
      }
      asm volatile("s_waitcnt lgkmcnt(0)" ::: "memory");
      __builtin_amdgcn_sched_barrier(0);
      // PV: A = P[q=li][kv], B = V^T rows from swizzled LDS
      const bf16x8 ap0 = *(const bf16x8*)&ps[w * 1152 + li * 72 + kg * 8];
      const bf16x8 ap1 = *(const bf16x8*)&ps[w * 1152 + li * 72 + 32 + kg * 8];
#pragma unroll
      for (int df = 0; df < 4; ++df) {
        const int row = df * 16 + li;
        const int rsw = (row & 7) * 8;
        const bf16x8 bv0 = *(const bf16x8*)&vb[row * 64 + ((kg * 8) ^ rsw)];
        const bf16x8 bv1 = *(const bf16x8*)&vb[row * 64 + ((32 + kg * 8) ^ rsw)];
        acc[df] = __builtin_amdgcn_mfma_f32_16x16x32_bf16(ap0, bv0, acc[df], 0, 0, 0);
        acc[df] = __builtin_amdgcn_mfma_f32_16x16x32_bf16(ap1, bv1, acc[df], 0, 0, 0);
      }
    }
  }
  // final per-row l; combine the two halves in LDS
  lsum += __shfl_xor(lsum, 16);
  lsum += __shfl_xor(lsum, 32);
  float m4[4], l4[4];
#pragma unroll
  for (int r = 0; r < 4; ++r) {
    const int src = (l & 48) | (kg * 4 + r);
    m4[r] = __shfl(m, src);
    l4[r] = __shfl(lsum, src);
  }
  __syncthreads();    // protect overlay region (kbuf) from in-loop readers
  if (hf == 1) {
#pragma unroll
    for (int df = 0; df < 4; ++df)
#pragma unroll
      for (int r = 0; r < 4; ++r)
        accbuf[(qsub * 16 + kg * 4 + r) * 67 + df * 16 + li] = acc[df][r];
    if (kg == 0) {
      mlbuf[(qsub * 16 + li) * 2 + 0] = m;
      mlbuf[(qsub * 16 + li) * 2 + 1] = lsum;
    }
  }
  __syncthreads();
  if (hf == 0) {
    float f0[4], f1[4], rL[4];
#pragma unroll
    for (int r = 0; r < 4; ++r) {
      const float m1 = mlbuf[(qsub * 16 + kg * 4 + r) * 2 + 0];
      const float l1 = mlbuf[(qsub * 16 + kg * 4 + r) * 2 + 1];
      const float M = fmaxf(m4[r], m1);
      f0[r] = EXP2(m4[r] - M);
      f1[r] = EXP2(m1 - M);
      rL[r] = __builtin_amdgcn_rcpf(l4[r] * f0[r] + l1 * f1[r]);
    }
#pragma unroll
    for (int df = 0; df < 4; ++df)
#pragma unroll
      for (int r = 0; r < 4; ++r) {
        const float a1 = accbuf[(qsub * 16 + kg * 4 + r) * 67 + df * 16 + li];
        const float o = (acc[df][r] * f0[r] + a1 * f1[r]) * rL[r];
        aoB[((size_t)b * NPIX + qrow0 + kg * 4 + r) * HID + hh * DH + df * 16 + li] = f2b(o);
      }
  }
}

// ---------------- Kernel 5: out projection GEMM (bf16 MFMA) ---------------------
// out[b][o][p] = sum_c aoB[p][c] * wob[o][c];  grid (144, 8), block 256
__global__ __launch_bounds__(256) void k_outg(
    const u16* __restrict__ aoB, const u16* __restrict__ wob, float* __restrict__ out)
{
  const int t = threadIdx.x, w = t >> 6, l = t & 63, li = l & 15, kg = l >> 4;
  const int wm = w >> 1, wn = w & 1;
  const int m0 = blockIdx.x * 32 + wm * 16;
  const int n0 = blockIdx.y * 32 + wn * 16;
  const u16* ap = aoB + (size_t)(m0 + li) * HID + kg * 8;
  const u16* bp = wob + (size_t)(n0 + li) * HID + kg * 8;
  f32x4 acc = {0.f, 0.f, 0.f, 0.f};
#pragma unroll
  for (int ks = 0; ks < 16; ++ks) {
    const bf16x8 af = *(const bf16x8*)(ap + ks * 32);
    const bf16x8 bf = *(const bf16x8*)(bp + ks * 32);
    acc = __builtin_amdgcn_mfma_f32_16x16x32_bf16(af, bf, acc, 0, 0, 0);
  }
  const int bb = (m0 >= NPIX) ? 1 : 0;
  const int pl = m0 - bb * NPIX + kg * 4;
  const int o = n0 + li;
  *(f32x4*)&out[((size_t)(bb * CDIM + o)) * NPIX + pl] = acc;
}

extern "C" void kernel_launch(void* const* d_in, const int* in_sizes, int n_in,
                              void* d_out, int out_size, void* d_ws, size_t ws_size,
                              hipStream_t stream)
{
  const float* x      = (const float*)d_in[0];
  const float* gamma  = (const float*)d_in[1];
  const float* mem_kv = (const float*)d_in[2];
  const float* wqkv   = (const float*)d_in[3];
  const float* wout   = (const float*)d_in[4];
  float* out = (float*)d_out;
  char* ws = (char*)d_ws;
  const size_t XNT = (size_t)BATCH * NPIX * CDIM * sizeof(u16);        // 2,359,296
  const size_t WB  = (size_t)(WQKV_E + WOUT_E) * sizeof(u16);          // 1,048,576
  const size_t QB  = (size_t)BATCH * NHEAD * NPIX * DH * sizeof(u16);  // 4,718,592
  const size_t KB  = (size_t)BATCH * NHEAD * NKV  * DH * sizeof(u16);  // 4,726,784
  const size_t VTB = (size_t)BATCH * NHEAD * DH * NKVP * sizeof(u16);  // 4,849,664
  u16* xnT = (u16*)ws;
  u16* wb  = (u16*)(ws + XNT);
  u16* q   = (u16*)(ws + XNT + WB);
  u16* kk  = (u16*)(ws + XNT + WB + QB);
  u16* vT  = (u16*)(ws + XNT + WB + QB + KB);
  u16* aoB = (u16*)(ws + XNT + WB + QB + KB + VTB);  // + 4,718,592 -> ~21.4 MB

  k_prep<<<dim3(336), dim3(256), 0, stream>>>(wqkv, wout, gamma, mem_kv, wb, kk, vT);
  k_norm<<<dim3(288), dim3(256), 0, stream>>>(x, xnT);
  k_qkv<<<dim3(72, 24), dim3(256), 0, stream>>>(xnT, wb, q, kk, vT);
  k_attn<<<dim3(576), dim3(512), 0, stream>>>(q, kk, vT, aoB);
  k_outg<<<dim3(144, 8), dim3(256), 0, stream>>>(aoB, wb + WQKV_E, out);
}